// Round 4
// baseline (82.118 us; speedup 1.0000x reference)
//
#include <hip/hip_runtime.h>

#define BLOCK 256
#define NPTS (8 * 65536)

// PPT=2: thread t in block b owns points p0 = b*512 + t, p1 = p0 + 256.
// 1024 blocks -> 4 blocks/CU -> 4 waves/SIMD.
// Weights are read at wave-uniform, unroll-constant addresses directly from
// global -> compiler scalarizes to s_load_dwordx{8,16} on the SMEM pipe,
// keeping both the LDS pipe and VMEM out of the inner loop (R3 was
// LDS-pipe-bound: 2 ds_reads/h/wave oversubscribed the per-CU LDS pipe 1.67x).
// The two points are carried as float2 so the backend can pack v_pk_fma_f32.
// sincos(theta) is block-uniform: computed once by lane 0, broadcast via LDS.

__global__ __launch_bounds__(BLOCK, 4) void cubeflow_fused(
    const float* __restrict__ input,
    const float* __restrict__ latent,
    const float* __restrict__ W1,
    const float* __restrict__ b1,
    const float* __restrict__ W2,
    const float* __restrict__ b2,
    float* __restrict__ out)
{
    __shared__ float sTrig[2];

    const int t     = threadIdx.x;
    const int base  = blockIdx.x * 512;
    const int batch = blockIdx.x >> 7;            // 128 blocks per batch
    const float theta = latent[batch] * 10.0f;    // uniform -> s_load + s-side mul

    if (t == 0) {
        sTrig[0] = cosf(theta);
        sTrig[1] = sinf(theta);
    }

    const int p0 = base + t;
    const int p1 = p0 + 256;

    // dense 12B/lane loads (dwordx3)
    const float* ip0 = input + 3 * p0;
    const float* ip1 = input + 3 * p1;
    float2 x0, x1, x2;
    x0.x = ip0[0]; x1.x = ip0[1]; x2.x = ip0[2];
    x0.y = ip1[0]; x1.y = ip1[1]; x2.y = ip1[2];

    float* __restrict__ out_eval  = out;             // NPTS
    float* __restrict__ out_con   = out + NPTS;      // NPTS*4
    float* __restrict__ out_probs = out + 5 * NPTS;  // NPTS*2

    __syncthreads();
    const float cth = sTrig[0];
    const float sth = sTrig[1];

    // ---- eval (closed-form Rz quadratics), paired ----
    {
        const float2 d0 = {x0.x - theta, x0.y - theta};
        const float2 d1 = x1;
        const float2 d2 = x2;
#pragma unroll
        for (int k = 0; k < 2; ++k) {
            const float e0 = k ? d0.y : d0.x;
            const float e1 = k ? d1.y : d1.x;
            const float e2 = k ? d2.y : d2.x;
            const float f1 = fmaf(1.4f * e0, e0, fmaf(1.4f * e1, e1, 0.2f * e2 * e2)) - 0.5f;
            const float c2x = fmaf(cth, e0,  sth * e1);
            const float c2y = fmaf(cth, e1, -sth * e0);
            const float c2z = e2 + 0.4f;
            const float f2 = fmaf(3.8f * c2x, c2x, fmaf(0.6f * c2y, c2y, 3.8f * c2z * c2z)) - 0.5f;
            const float c3x = fmaf(cth, e0, -sth * e1);
            const float c3y = fmaf(sth, e0,  cth * e1);
            const float c3z = e2 - 0.6f;
            const float f3 = fmaf(0.35f * c3x, c3x, fmaf(2.8f * c3y, c3y, 2.8f * c3z * c3z)) - 0.5f;
            const float ev = fminf(f1, fminf(f2, f3));
            const int   p  = k ? p1 : p0;
            out_eval[p] = ev;
            *reinterpret_cast<float4*>(out_con + 4 * p) =
                make_float4(k ? x0.y : x0.x, k ? x1.y : x1.x, k ? x2.y : x2.x, theta);
        }
    }

    // ---- MLP: h = relu(W1[:, :3]x + (b1 + theta*W1[:,3])); probs = W2 h + b2 ----
    const float b20 = b2[0];
    const float b21 = b2[1];
    float2 A0 = {b20, b20};
    float2 A1 = {b21, b21};

#pragma unroll 16
    for (int h = 0; h < 128; ++h) {
        // uniform unroll-constant addresses -> s_load batches
        const float w0  = W1[4 * h + 0];
        const float w1  = W1[4 * h + 1];
        const float w2v = W1[4 * h + 2];
        const float bh  = fmaf(W1[4 * h + 3], theta, b1[h]);  // uniform fold
        const float w20 = W2[h];
        const float w21 = W2[128 + h];

        float2 hv;
        hv.x = fmaf(x0.x, w0, fmaf(x1.x, w1, fmaf(x2.x, w2v, bh)));
        hv.y = fmaf(x0.y, w0, fmaf(x1.y, w1, fmaf(x2.y, w2v, bh)));
        hv.x = fmaxf(hv.x, 0.0f);
        hv.y = fmaxf(hv.y, 0.0f);
        A0.x = fmaf(hv.x, w20, A0.x);
        A0.y = fmaf(hv.y, w20, A0.y);
        A1.x = fmaf(hv.x, w21, A1.x);
        A1.y = fmaf(hv.y, w21, A1.y);
    }

    *reinterpret_cast<float2*>(out_probs + 2 * p0) = make_float2(A0.x, A1.x);
    *reinterpret_cast<float2*>(out_probs + 2 * p1) = make_float2(A0.y, A1.y);
}

extern "C" void kernel_launch(void* const* d_in, const int* in_sizes, int n_in,
                              void* d_out, int out_size, void* d_ws, size_t ws_size,
                              hipStream_t stream) {
    const float* input  = (const float*)d_in[0];
    const float* latent = (const float*)d_in[1];
    const float* W1     = (const float*)d_in[2];
    const float* b1     = (const float*)d_in[3];
    const float* W2     = (const float*)d_in[4];
    const float* b2     = (const float*)d_in[5];
    float* out = (float*)d_out;

    const int nblocks = NPTS / 512;   // 1024
    hipLaunchKernelGGL(cubeflow_fused, dim3(nblocks), dim3(BLOCK), 0, stream,
                       input, latent, W1, b1, W2, b2, out);
}

// Round 5
// 79.748 us; speedup vs baseline: 1.0297x; 1.0297x over previous
//
#include <hip/hip_runtime.h>

#define NPTS (8 * 65536)

// Block: 512 threads, 1024 points.
//   split = t>>7 (0..3): hidden-group h in [split*32, split*32+32)
//   q     = t&127      : points p(k) = blk*1024 + q + 128k, k=0..7
// All 4 splits load the same 8 points (12 KB/block, L1-resident); each split
// computes partial (a0,a1) over its 32 hidden units; 4-way reduce via LDS.
// Each thread owns 2 points (k = 2*split, 2*split+1) for eval/con/probs stores.
// Weights in LDS: sW1[h] = {w0,w1,w2, b1+theta*w3} (1 ds_read_b128 per h),
// sW2 packs TWO h's W2 pairs per float4 (1 ds_read_b128 per 2 h) ->
// 1.5 b128 per h per wave, ~9.2k LDS cyc/CU < ~12.6k VALU cyc/SIMD: VALU-bound.

__global__ __launch_bounds__(512, 4) void cubeflow_fused(
    const float* __restrict__ input,
    const float* __restrict__ latent,
    const float* __restrict__ W1,
    const float* __restrict__ b1,
    const float* __restrict__ W2,
    const float* __restrict__ b2,
    float* __restrict__ out)
{
    __shared__ float4 sW1[128];      // {w0,w1,w2, b1 + theta*w3}
    __shared__ float4 sW2[64];       // {w20[2h], w21[2h], w20[2h+1], w21[2h+1]}
    __shared__ float2 sPart[4][1024];

    const int t     = threadIdx.x;
    const int split = t >> 7;
    const int q     = t & 127;
    const int base  = blockIdx.x * 1024;
    const int batch = blockIdx.x >> 6;            // 64 blocks per batch
    const float theta = latent[batch] * 10.0f;

    // ---- stage weights (threads 0..127) ----
    if (t < 128) {
        float4 w;
        w.x = W1[4 * t + 0];
        w.y = W1[4 * t + 1];
        w.z = W1[4 * t + 2];
        w.w = fmaf(W1[4 * t + 3], theta, b1[t]);
        sW1[t] = w;
        if (t < 64)
            sW2[t] = make_float4(W2[2 * t], W2[128 + 2 * t],
                                 W2[2 * t + 1], W2[128 + 2 * t + 1]);
    }

    // ---- load 8 points (dwordx3, lane-contiguous) ----
    float x0[8], x1[8], x2[8];
#pragma unroll
    for (int k = 0; k < 8; ++k) {
        const float* ip = input + 3 * (base + q + 128 * k);
        x0[k] = ip[0];
        x1[k] = ip[1];
        x2[k] = ip[2];
    }

    float* __restrict__ out_eval  = out;             // NPTS
    float* __restrict__ out_con   = out + NPTS;      // NPTS*4
    float* __restrict__ out_probs = out + 5 * NPTS;  // NPTS*2

    // ---- eval + con for this thread's 2 owned points ----
    const int ko = split * 2;
    {
        float sth, cth;
        sincosf(theta, &sth, &cth);
#pragma unroll
        for (int kk = 0; kk < 2; ++kk) {
            const int k = ko + kk;
            const float d0 = x0[k] - theta;
            const float d1 = x1[k];
            const float d2 = x2[k];
            const float f1 = fmaf(1.4f * d0, d0, fmaf(1.4f * d1, d1, 0.2f * d2 * d2)) - 0.5f;
            const float c2x = fmaf(cth, d0,  sth * d1);
            const float c2y = fmaf(cth, d1, -sth * d0);
            const float c2z = d2 + 0.4f;
            const float f2 = fmaf(3.8f * c2x, c2x, fmaf(0.6f * c2y, c2y, 3.8f * c2z * c2z)) - 0.5f;
            const float c3x = fmaf(cth, d0, -sth * d1);
            const float c3y = fmaf(sth, d0,  cth * d1);
            const float c3z = d2 - 0.6f;
            const float f3 = fmaf(0.35f * c3x, c3x, fmaf(2.8f * c3y, c3y, 2.8f * c3z * c3z)) - 0.5f;
            const int p = base + q + 128 * k;
            out_eval[p] = fminf(f1, fminf(f2, f3));
            *reinterpret_cast<float4*>(out_con + 4 * p) =
                make_float4(x0[k], x1[k], x2[k], theta);
        }
    }

    __syncthreads();   // weights staged

    // ---- MLP partials over this split's 32 hidden units, 2 h per iter ----
    float a0[8], a1[8];
#pragma unroll
    for (int k = 0; k < 8; ++k) { a0[k] = 0.0f; a1[k] = 0.0f; }

    const int hbase = split * 32;
#pragma unroll 4
    for (int hh = 0; hh < 16; ++hh) {
        const float4 wA = sW1[hbase + 2 * hh];       // ds_read_b128
        const float4 wB = sW1[hbase + 2 * hh + 1];   // ds_read_b128
        const float4 w2 = sW2[split * 16 + hh];      // ds_read_b128 (covers 2 h)
#pragma unroll
        for (int k = 0; k < 8; ++k) {
            float hA = fmaf(x0[k], wA.x, fmaf(x1[k], wA.y, fmaf(x2[k], wA.z, wA.w)));
            hA = fmaxf(hA, 0.0f);
            a0[k] = fmaf(hA, w2.x, a0[k]);
            a1[k] = fmaf(hA, w2.y, a1[k]);
            float hB = fmaf(x0[k], wB.x, fmaf(x1[k], wB.y, fmaf(x2[k], wB.z, wB.w)));
            hB = fmaxf(hB, 0.0f);
            a0[k] = fmaf(hB, w2.z, a0[k]);
            a1[k] = fmaf(hB, w2.w, a1[k]);
        }
    }

    // ---- publish partials, 4-way reduce, owner stores ----
#pragma unroll
    for (int k = 0; k < 8; ++k)
        sPart[split][q + 128 * k] = make_float2(a0[k], a1[k]);
    __syncthreads();

    {
        const float b20 = b2[0];
        const float b21 = b2[1];
#pragma unroll
        for (int kk = 0; kk < 2; ++kk) {
            const int pb = q + 128 * (ko + kk);
            float r0 = b20, r1 = b21;
#pragma unroll
            for (int s = 0; s < 4; ++s) {
                const float2 v = sPart[s][pb];
                r0 += v.x;
                r1 += v.y;
            }
            *reinterpret_cast<float2*>(out_probs + 2 * (base + pb)) =
                make_float2(r0, r1);
        }
    }
}

extern "C" void kernel_launch(void* const* d_in, const int* in_sizes, int n_in,
                              void* d_out, int out_size, void* d_ws, size_t ws_size,
                              hipStream_t stream) {
    const float* input  = (const float*)d_in[0];
    const float* latent = (const float*)d_in[1];
    const float* W1     = (const float*)d_in[2];
    const float* b1     = (const float*)d_in[3];
    const float* W2     = (const float*)d_in[4];
    const float* b2     = (const float*)d_in[5];
    float* out = (float*)d_out;

    const int nblocks = NPTS / 1024;   // 512
    hipLaunchKernelGGL(cubeflow_fused, dim3(nblocks), dim3(512), 0, stream,
                       input, latent, W1, b1, W2, b2, out);
}

// Round 6
// 79.463 us; speedup vs baseline: 1.0334x; 1.0036x over previous
//
#include <hip/hip_runtime.h>

typedef float v2f __attribute__((ext_vector_type(2)));

#define NPTS (8 * 65536)
#define BLOCK 512
#define PPB   2048   // points per block

// 256 blocks (1 per CU), 512 threads each, 2048 points per block.
//   half = t>>8 : hidden-group h in [half*64, half*64+64)
//   q    = t&255: points p(k) = blk*2048 + q + 256k, k=0..7 (4 float2 pairs)
// MLP math is packed fp32 (v_pk_fma_f32 via float2 ext-vectors +
// __builtin_elementwise_fma): 2 FMAs per VALU issue slot -> MLP issue floor
// halves (~5.1 -> ~3.0 us), converging on the ~3.3 us HBM floor.
// Weights in LDS: sW1[h]={w0,w1,w2,b1+theta*w3} (b128/h), sW2 packs two h's
// W2 pairs per float4 (b128/2h) -> 1.5 b128 per 2h per wave; at 8 waves/CU
// LDS pipe ~4.6k cyc/CU < VALU ~6.7k cyc/SIMD: VALU-bound even packed.
// Each half owns 4 of the 8 k's for eval/con/probs stores; partials for the
// other half's k-set go through a 16 KB LDS exchange.

__global__ __launch_bounds__(BLOCK, 2) void cubeflow_fused(
    const float* __restrict__ input,
    const float* __restrict__ latent,
    const float* __restrict__ W1,
    const float* __restrict__ b1,
    const float* __restrict__ W2,
    const float* __restrict__ b2,
    float* __restrict__ out)
{
    __shared__ float4 sW1[128];      // {w0,w1,w2, b1 + theta*w3}
    __shared__ float4 sW2[64];       // {w20[2h],w21[2h], w20[2h+1],w21[2h+1]}
    __shared__ float2 sPart[PPB];    // other-half partials, one writer per point

    const int t     = threadIdx.x;
    const int half  = t >> 8;
    const int q     = t & 255;
    const int base  = blockIdx.x * PPB;
    const int batch = blockIdx.x >> 5;            // 32 blocks per batch
    const float theta = latent[batch] * 10.0f;

    // ---- stage weights (threads 0..127) ----
    if (t < 128) {
        float4 w;
        w.x = W1[4 * t + 0];
        w.y = W1[4 * t + 1];
        w.z = W1[4 * t + 2];
        w.w = fmaf(W1[4 * t + 3], theta, b1[t]);
        sW1[t] = w;
        if (t < 64)
            sW2[t] = make_float4(W2[2 * t],     W2[128 + 2 * t],
                                 W2[2 * t + 1], W2[128 + 2 * t + 1]);
    }

    // ---- load 8 points (12B/lane, lane-contiguous) ----
    float x0[8], x1[8], x2[8];
#pragma unroll
    for (int k = 0; k < 8; ++k) {
        const float* ip = input + 3 * (base + q + 256 * k);
        x0[k] = ip[0];
        x1[k] = ip[1];
        x2[k] = ip[2];
    }

    float* __restrict__ out_eval  = out;             // NPTS
    float* __restrict__ out_con   = out + NPTS;      // NPTS*4
    float* __restrict__ out_probs = out + 5 * NPTS;  // NPTS*2

    // ---- eval + con for this half's 4 owned points ----
    const int ko = half * 4;
    {
        float sth, cth;
        sincosf(theta, &sth, &cth);
#pragma unroll
        for (int kk = 0; kk < 4; ++kk) {
            const int k = ko + kk;
            const float d0 = x0[k] - theta;
            const float d1 = x1[k];
            const float d2 = x2[k];
            const float f1 = fmaf(1.4f * d0, d0, fmaf(1.4f * d1, d1, 0.2f * d2 * d2)) - 0.5f;
            const float c2x = fmaf(cth, d0,  sth * d1);
            const float c2y = fmaf(cth, d1, -sth * d0);
            const float c2z = d2 + 0.4f;
            const float f2 = fmaf(3.8f * c2x, c2x, fmaf(0.6f * c2y, c2y, 3.8f * c2z * c2z)) - 0.5f;
            const float c3x = fmaf(cth, d0, -sth * d1);
            const float c3y = fmaf(sth, d0,  cth * d1);
            const float c3z = d2 - 0.6f;
            const float f3 = fmaf(0.35f * c3x, c3x, fmaf(2.8f * c3y, c3y, 2.8f * c3z * c3z)) - 0.5f;
            const int p = base + q + 256 * k;
            out_eval[p] = fminf(f1, fminf(f2, f3));
            *reinterpret_cast<float4*>(out_con + 4 * p) =
                make_float4(x0[k], x1[k], x2[k], theta);
        }
    }

    // ---- pack points into float2 pairs ----
    v2f X0[4], X1[4], X2[4];
#pragma unroll
    for (int j = 0; j < 4; ++j) {
        X0[j] = v2f{x0[2 * j], x0[2 * j + 1]};
        X1[j] = v2f{x1[2 * j], x1[2 * j + 1]};
        X2[j] = v2f{x2[2 * j], x2[2 * j + 1]};
    }

    __syncthreads();   // weights staged

    // ---- MLP partials over this half's 64 hidden units (packed fp32) ----
    v2f A0[4], A1[4];
#pragma unroll
    for (int j = 0; j < 4; ++j) { A0[j] = 0.0f; A1[j] = 0.0f; }

    const v2f zero = 0.0f;
    const int hbase = half * 64;
#pragma unroll 8
    for (int hh = 0; hh < 32; ++hh) {
        const float4 wA = sW1[hbase + 2 * hh];       // ds_read_b128
        const float4 wB = sW1[hbase + 2 * hh + 1];   // ds_read_b128
        const float4 w2 = sW2[(hbase >> 1) + hh];    // ds_read_b128 (2 h)
        const v2f wAx = wA.x, wAy = wA.y, wAz = wA.z, wAw = wA.w;
        const v2f wBx = wB.x, wBy = wB.y, wBz = wB.z, wBw = wB.w;
        const v2f w20A = w2.x, w21A = w2.y, w20B = w2.z, w21B = w2.w;
#pragma unroll
        for (int j = 0; j < 4; ++j) {
            v2f hA = __builtin_elementwise_fma(X0[j], wAx,
                       __builtin_elementwise_fma(X1[j], wAy,
                         __builtin_elementwise_fma(X2[j], wAz, wAw)));
            hA = __builtin_elementwise_max(hA, zero);
            A0[j] = __builtin_elementwise_fma(hA, w20A, A0[j]);
            A1[j] = __builtin_elementwise_fma(hA, w21A, A1[j]);
            v2f hB = __builtin_elementwise_fma(X0[j], wBx,
                       __builtin_elementwise_fma(X1[j], wBy,
                         __builtin_elementwise_fma(X2[j], wBz, wBw)));
            hB = __builtin_elementwise_max(hB, zero);
            A0[j] = __builtin_elementwise_fma(hB, w20B, A0[j]);
            A1[j] = __builtin_elementwise_fma(hB, w21B, A1[j]);
        }
    }

    // ---- publish partials for the OTHER half's owned k-set ----
    const int kpub = (1 - half) * 4;
#pragma unroll
    for (int kk = 0; kk < 4; ++kk) {
        const int k = kpub + kk;
        const int j = k >> 1;
        const float p0 = (k & 1) ? A0[j].y : A0[j].x;
        const float p1 = (k & 1) ? A1[j].y : A1[j].x;
        sPart[q + 256 * k] = make_float2(p0, p1);
    }
    __syncthreads();

    // ---- owner: reduce + bias + store ----
    {
        const float b20 = b2[0];
        const float b21 = b2[1];
#pragma unroll
        for (int kk = 0; kk < 4; ++kk) {
            const int k  = ko + kk;
            const int j  = k >> 1;
            const int pb = q + 256 * k;
            const float2 o = sPart[pb];
            const float mine0 = (k & 1) ? A0[j].y : A0[j].x;
            const float mine1 = (k & 1) ? A1[j].y : A1[j].x;
            *reinterpret_cast<float2*>(out_probs + 2 * (base + pb)) =
                make_float2(b20 + mine0 + o.x, b21 + mine1 + o.y);
        }
    }
}

extern "C" void kernel_launch(void* const* d_in, const int* in_sizes, int n_in,
                              void* d_out, int out_size, void* d_ws, size_t ws_size,
                              hipStream_t stream) {
    const float* input  = (const float*)d_in[0];
    const float* latent = (const float*)d_in[1];
    const float* W1     = (const float*)d_in[2];
    const float* b1     = (const float*)d_in[3];
    const float* W2     = (const float*)d_in[4];
    const float* b2     = (const float*)d_in[5];
    float* out = (float*)d_out;

    const int nblocks = NPTS / PPB;   // 256
    hipLaunchKernelGGL(cubeflow_fused, dim3(nblocks), dim3(BLOCK), 0, stream,
                       input, latent, W1, b1, W2, b2, out);
}